// Round 4
// baseline (728.787 us; speedup 1.0000x reference)
//
#include <hip/hip_runtime.h>

#define DIM 4096
#define HD 128
#define NH 32
#define NKV 8
#define SEQ 2048
#define BATCH 2
#define MTOT (BATCH*SEQ)   // 4096 rows total
#define GK DIM             // K dim of every GEMM

typedef __bf16 bf16;
typedef __bf16 bf16x4 __attribute__((ext_vector_type(4)));
typedef __bf16 bf16x8 __attribute__((ext_vector_type(8)));
typedef float f32x4 __attribute__((ext_vector_type(4)));

__device__ __forceinline__ void gload_lds16(const void* g, void* l) {
    __builtin_amdgcn_global_load_lds(
        (const __attribute__((address_space(1))) void*)g,
        (__attribute__((address_space(3))) void*)l, 16, 0, 0);
}

// ---------------- fp32 -> bf16 flat convert (x) ----------------
__global__ __launch_bounds__(256) void conv_bf16(const float* __restrict__ in,
                                                 bf16* __restrict__ out, int n8) {
    int i = blockIdx.x * 256 + threadIdx.x;
    if (i >= n8) return;
    const float4* p = (const float4*)(in + (size_t)i * 8);
    float4 a = p[0], b = p[1];
    bf16x8 v;
    v[0]=(bf16)a.x; v[1]=(bf16)a.y; v[2]=(bf16)a.z; v[3]=(bf16)a.w;
    v[4]=(bf16)b.x; v[5]=(bf16)b.y; v[6]=(bf16)b.z; v[7]=(bf16)b.w;
    *(bf16x8*)(out + (size_t)i * 8) = v;
}

// ---------------- fp32 [K][N] -> bf16 [N][K] transpose-convert ----------------
__global__ __launch_bounds__(256) void tconv(const float* __restrict__ in,
                                             bf16* __restrict__ out, int N, int K) {
    __shared__ float t[32][33];
    int bx = blockIdx.x, by = blockIdx.y;
    int tx = threadIdx.x, ty = threadIdx.y;
    int col = bx * 32 + tx;
#pragma unroll
    for (int r = 0; r < 4; ++r) {
        int row = by * 32 + ty + r * 8;
        t[ty + r * 8][tx] = in[(size_t)row * N + col];
    }
    __syncthreads();
#pragma unroll
    for (int r = 0; r < 4; ++r) {
        int n = bx * 32 + ty + r * 8;
        int k = by * 32 + tx;
        out[(size_t)n * K + k] = (bf16)t[tx][ty + r * 8];
    }
}

// ---------------- RoPE in-place on bf16 buffer ----------------
__global__ __launch_bounds__(256) void rope_k(bf16* __restrict__ buf, int shift, int n8) {
    int i = blockIdx.x * 256 + threadIdx.x;
    if (i >= n8) return;
    size_t base = (size_t)i * 8;
    int col = (int)(base & ((1u << shift) - 1));
    int pos = (int)((base >> shift) & (SEQ - 1));
    int d0 = col & (HD - 1);
    bf16x8 v = *(const bf16x8*)(buf + base);
    float f[8];
#pragma unroll
    for (int j = 0; j < 8; ++j) f[j] = (float)v[j];
    const float nl2t = -13.287712379549449f / 64.f;  // -log2(theta)/(HD/2)
#pragma unroll
    for (int j = 0; j < 4; ++j) {
        float inv = exp2f(nl2t * (float)((d0 >> 1) + j));
        float ang = (float)pos * inv;
        float sn, cs;
        sincosf(ang, &sn, &cs);
        float x0 = f[2 * j], x1 = f[2 * j + 1];
        f[2 * j]     = x0 * cs - x1 * sn;
        f[2 * j + 1] = x0 * sn + x1 * cs;
    }
    bf16x8 ov;
#pragma unroll
    for (int j = 0; j < 8; ++j) ov[j] = (bf16)f[j];
    *(bf16x8*)(buf + base) = ov;
}

// ---------------- bf16 GEMM: C[M,N] = A[M,K] * Bt[N,K]^T  (m97 structure) ----
template <bool F32OUT>
__global__ __launch_bounds__(256) void gemm_bt(const bf16* __restrict__ A,
                                               const bf16* __restrict__ Bt,
                                               void* __restrict__ out0, int N) {
    __shared__ alignas(16) bf16 sA[2][128 * 32];
    __shared__ alignas(16) bf16 sB[2][128 * 32];
    const int tid = threadIdx.x;
    const int lane = tid & 63, wid = tid >> 6;
    const int wm = wid >> 1, wn = wid & 1;
    const int m0 = blockIdx.y * 128, n0 = blockIdx.x * 128;

    auto stage = [&](int buf, int kt) {
#pragma unroll
        for (int it = 0; it < 2; ++it) {
            int slot = it * 256 + tid;
            int row = slot >> 2, s = slot & 3;
            gload_lds16(A + (size_t)(m0 + row) * GK + kt * 32 + s * 8, &sA[buf][slot * 8]);
            gload_lds16(Bt + (size_t)(n0 + row) * GK + kt * 32 + s * 8, &sB[buf][slot * 8]);
        }
    };

    f32x4 acc[4][4] = {};
    stage(0, 0);
    __syncthreads();
    int cur = 0;
    for (int kt = 0; kt < GK / 32; ++kt) {
        if (kt + 1 < GK / 32) stage(cur ^ 1, kt + 1);
        bf16x8 aF[4], bF[4];
#pragma unroll
        for (int i = 0; i < 4; ++i) {
            aF[i] = *(const bf16x8*)&sA[cur][(wm * 64 + i * 16 + (lane & 15)) * 32 + (lane >> 4) * 8];
            bF[i] = *(const bf16x8*)&sB[cur][(wn * 64 + i * 16 + (lane & 15)) * 32 + (lane >> 4) * 8];
        }
#pragma unroll
        for (int mi = 0; mi < 4; ++mi)
#pragma unroll
            for (int ni = 0; ni < 4; ++ni)
                acc[mi][ni] = __builtin_amdgcn_mfma_f32_16x16x32_bf16(aF[mi], bF[ni], acc[mi][ni], 0, 0, 0);
        __syncthreads();
        cur ^= 1;
    }
#pragma unroll
    for (int mi = 0; mi < 4; ++mi) {
#pragma unroll
        for (int ni = 0; ni < 4; ++ni) {
#pragma unroll
            for (int r = 0; r < 4; ++r) {
                int row = m0 + wm * 64 + mi * 16 + (lane >> 4) * 4 + r;
                int col = n0 + wn * 64 + ni * 16 + (lane & 15);
                float v = acc[mi][ni][r];
                if constexpr (F32OUT) {
                    ((float*)out0)[(size_t)row * N + col] = v;
                } else {
                    ((bf16*)out0)[(size_t)row * N + col] = (bf16)v;
                }
            }
        }
    }
}

// ---------------- flash attention, GQA, causal ----------------
// grid: 512 = b(2) * h(32) * pair(8); 8 waves x 16 q-rows = 128 q-rows/pass;
// each block runs two passes (q-tile pr and 15-pr) -> exactly 34 KV rounds each.
// Swapped QK^T (S^T): softmax rows lane-local, P-writes packed b64.
__global__ __launch_bounds__(512, 4) void attn_fwd(const bf16* __restrict__ q,
                                                   const bf16* __restrict__ k,
                                                   const bf16* __restrict__ vt,
                                                   bf16* __restrict__ o) {
    __shared__ alignas(16) bf16 sK[2][64 * 128];   // [kv][d], XOR-swizzled source
    __shared__ alignas(16) bf16 sV[2][128 * 64];   // [d][kv], XOR-swizzled source
    __shared__ alignas(16) bf16 sP[8][16 * 64];    // per-wave P[q][kv], swizzled
    const int tid = threadIdx.x, lane = tid & 63, wid = tid >> 6;
    const int bi = blockIdx.x;
    const int pr = bi & 7;
    const int h = (bi >> 3) & 31;
    const int b = bi >> 8;
    const int kvh = h >> 2;
    const float scale = 0.08838834764831845f;  // 1/sqrt(128)

    const bf16* kb0 = k + (size_t)b * SEQ * (NKV * HD) + kvh * HD;
    const bf16* vb0 = vt + (size_t)(kvh * HD) * MTOT + (size_t)b * SEQ;

    auto stage = [&](int bf, int tt) {
        // K tile [64][128]: 1024 16B-slots, src slot = phys ^ (row&7)
#pragma unroll
        for (int it = 0; it < 2; ++it) {
            int slot = it * 512 + tid;
            int row = slot >> 4, s = slot & 15;
            gload_lds16(kb0 + (size_t)(tt * 64 + row) * (NKV * HD) + ((s ^ (row & 7)) * 8),
                        &sK[bf][slot * 8]);
        }
        // V^T tile [128][64] from vt[vdim][token] (row stride MTOT)
#pragma unroll
        for (int it = 0; it < 2; ++it) {
            int slot = it * 512 + tid;
            int row = slot >> 3, s = slot & 7;
            gload_lds16(vb0 + (size_t)row * MTOT + tt * 64 + ((s ^ (row & 7)) * 8),
                        &sV[bf][slot * 8]);
        }
    };

    auto pass = [&](int qt) {
        const int qb0 = qt * 128;
        const int nt = 2 * qt + 2;
        const bf16* qp = q + ((size_t)(b * SEQ + qb0 + wid * 16 + (lane & 15))) * DIM
                           + h * HD + (lane >> 4) * 8;
        bf16x8 aQ[4];
#pragma unroll
        for (int ks = 0; ks < 4; ++ks) aQ[ks] = *(const bf16x8*)(qp + ks * 32);

        f32x4 accO[8] = {};
        float m_r = -1e30f, l_r = 0.f;   // per-lane: q-col = lane&15 (uniform over hi)
        const int qglob = qb0 + wid * 16 + (lane & 15);
        char* pb = (char*)&sP[wid][0];
        const int q7s = (lane & 7) << 4;
        const int hi = lane >> 4;

        stage(0, 0);
        __syncthreads();
        int cur = 0;
        for (int tt = 0; tt < nt; ++tt) {
            if (tt + 1 < nt) stage(cur ^ 1, tt + 1);
            // skip tiles fully above this wave's diagonal (identity contribution)
            if (tt * 64 <= qb0 + wid * 16 + 15) {
                // S^T = mfma(K, Q): frag nt2 -> rows kv = tt*64+nt2*16+hi*4+r, col q = lane&15
                f32x4 accS[4] = {};
#pragma unroll
                for (int nt2 = 0; nt2 < 4; ++nt2) {
                    int kr = nt2 * 16 + (lane & 15);
#pragma unroll
                    for (int ks = 0; ks < 4; ++ks) {
                        int slog = ks * 4 + hi;
                        bf16x8 bK = *(const bf16x8*)&sK[cur][kr * 128 + ((slog ^ (kr & 7)) * 8)];
                        accS[nt2] = __builtin_amdgcn_mfma_f32_16x16x32_bf16(bK, aQ[ks], accS[nt2], 0, 0, 0);
                    }
                }

                // scale + causal mask + lane-local max over 16 kv values
                const bool diag = (tt * 64 + 63 > qb0 + wid * 16);
                const int kvb = tt * 64 + hi * 4;
                float mx = -1e30f;
#pragma unroll
                for (int nt2 = 0; nt2 < 4; ++nt2)
#pragma unroll
                    for (int r = 0; r < 4; ++r) {
                        float v = accS[nt2][r] * scale;
                        if (diag && (kvb + nt2 * 16 + r > qglob)) v = -1e30f;
                        accS[nt2][r] = v;
                        mx = fmaxf(mx, v);
                    }
                mx = fmaxf(mx, __shfl_xor(mx, 16, 64));
                mx = fmaxf(mx, __shfl_xor(mx, 32, 64));

                float mn = fmaxf(m_r, mx);
                float al = __expf(m_r - mn);
                m_r = mn;
                float rs = 0.f;
#pragma unroll
                for (int nt2 = 0; nt2 < 4; ++nt2)
#pragma unroll
                    for (int r = 0; r < 4; ++r) {
                        float p = __expf(accS[nt2][r] - mn);
                        accS[nt2][r] = p;
                        rs += p;
                    }
                rs += __shfl_xor(rs, 16, 64);
                rs += __shfl_xor(rs, 32, 64);
                l_r = l_r * al + rs;

                // rescale accO: its q-row for reg r is hi*4+r -> fetch al from lane hi*4+r
                float al4[4];
#pragma unroll
                for (int r = 0; r < 4; ++r) al4[r] = __shfl(al, hi * 4 + r, 64);
#pragma unroll
                for (int d2 = 0; d2 < 8; ++d2)
#pragma unroll
                    for (int r = 0; r < 4; ++r) accO[d2][r] *= al4[r];

                // P-write: lane holds 4 contiguous kv per frag -> b64 stores
                // byte = q*128 + ((kvl*2) ^ ((q&7)<<4)), q = lane&15
#pragma unroll
                for (int nt2 = 0; nt2 < 4; ++nt2) {
                    bf16x4 pv;
                    pv[0] = (bf16)accS[nt2][0]; pv[1] = (bf16)accS[nt2][1];
                    pv[2] = (bf16)accS[nt2][2]; pv[3] = (bf16)accS[nt2][3];
                    *(bf16x4*)(pb + (lane & 15) * 128 + ((nt2 * 32 + hi * 8) ^ q7s)) = pv;
                }

                // PV: O[16 x 128] += P[16 x 64] * V[64 x 128]
                bf16x8 aP[2];
#pragma unroll
                for (int kk = 0; kk < 2; ++kk)
                    aP[kk] = *(const bf16x8*)(pb + (lane & 15) * 128 + ((kk * 64 + hi * 16) ^ q7s));
#pragma unroll
                for (int d2 = 0; d2 < 8; ++d2) {
#pragma unroll
                    for (int kk = 0; kk < 2; ++kk) {
                        int dv = d2 * 16 + (lane & 15);
                        int phys = (kk * 4 + hi) ^ (dv & 7);
                        bf16x8 bV = *(const bf16x8*)&sV[cur][dv * 64 + phys * 8];
                        accO[d2] = __builtin_amdgcn_mfma_f32_16x16x32_bf16(aP[kk], bV, accO[d2], 0, 0, 0);
                    }
                }
            }
            __syncthreads();
            cur ^= 1;
        }

        // epilogue: normalize + store bf16 (accO q-row for reg r = hi*4+r)
        float linv[4];
#pragma unroll
        for (int r = 0; r < 4; ++r) linv[r] = 1.f / __shfl(l_r, hi * 4 + r, 64);
        size_t orow = (size_t)(b * SEQ + qb0 + wid * 16 + hi * 4) * DIM
                    + h * HD + (lane & 15);
#pragma unroll
        for (int d2 = 0; d2 < 8; ++d2)
#pragma unroll
            for (int r = 0; r < 4; ++r)
                o[orow + (size_t)r * DIM + d2 * 16] = (bf16)(accO[d2][r] * linv[r]);
    };

    pass(pr);
    pass(15 - pr);
}

// ---------------- launch ----------------
extern "C" void kernel_launch(void* const* d_in, const int* in_sizes, int n_in,
                              void* d_out, int out_size, void* d_ws, size_t ws_size,
                              hipStream_t stream) {
    const float* x  = (const float*)d_in[0];
    const float* wq = (const float*)d_in[1];
    const float* wk = (const float*)d_in[2];
    const float* wv = (const float*)d_in[3];
    const float* wo = (const float*)d_in[4];
    float* out = (float*)d_out;

    char* ws = (char*)d_ws;
    size_t off = 0;
    bf16* xb  = (bf16*)(ws + off); off += (size_t)MTOT * DIM * 2;   // 32 MiB (reused as attn_out)
    bf16* wqt = (bf16*)(ws + off); off += (size_t)DIM * DIM * 2;    // 32 MiB (reused as wo_t)
    bf16* wkt = (bf16*)(ws + off); off += (size_t)1024 * DIM * 2;   // 8 MiB
    bf16* wvt = (bf16*)(ws + off); off += (size_t)1024 * DIM * 2;   // 8 MiB
    bf16* qb  = (bf16*)(ws + off); off += (size_t)MTOT * DIM * 2;   // 32 MiB
    bf16* kb  = (bf16*)(ws + off); off += (size_t)MTOT * 1024 * 2;  // 8 MiB
    bf16* vtb = (bf16*)(ws + off); off += (size_t)MTOT * 1024 * 2;  // 8 MiB  V^T [1024][4096]
    bf16* ao = xb;  // attention output reuses x_bf16

    dim3 tb(32, 8);
    conv_bf16<<<(MTOT * DIM / 8) / 256, 256, 0, stream>>>(x, xb, MTOT * DIM / 8);
    tconv<<<dim3(DIM / 32, DIM / 32), tb, 0, stream>>>(wq, wqt, DIM, DIM);
    tconv<<<dim3(1024 / 32, DIM / 32), tb, 0, stream>>>(wk, wkt, 1024, DIM);
    tconv<<<dim3(1024 / 32, DIM / 32), tb, 0, stream>>>(wv, wvt, 1024, DIM);

    gemm_bt<false><<<dim3(DIM / 128, MTOT / 128), 256, 0, stream>>>(xb, wqt, qb, DIM);
    gemm_bt<false><<<dim3(1024 / 128, MTOT / 128), 256, 0, stream>>>(xb, wkt, kb, 1024);
    // V^T[vdim][token] = wvt[vdim][k] * xb[token][k]^T  -> coalesced row-major V^T
    gemm_bt<false><<<dim3(MTOT / 128, 1024 / 128), 256, 0, stream>>>(wvt, xb, vtb, MTOT);

    rope_k<<<(MTOT * DIM / 8) / 256, 256, 0, stream>>>(qb, 12, MTOT * DIM / 8);
    rope_k<<<(MTOT * 1024 / 8) / 256, 256, 0, stream>>>(kb, 10, MTOT * 1024 / 8);

    tconv<<<dim3(DIM / 32, DIM / 32), tb, 0, stream>>>(wo, wqt, DIM, DIM);  // wo_t -> wqt space

    attn_fwd<<<BATCH * NH * 8, 512, 0, stream>>>(qb, kb, vtb, ao);

    gemm_bt<true><<<dim3(DIM / 128, MTOT / 128), 256, 0, stream>>>(ao, wqt, out, DIM);
}

// Round 5
// 621.600 us; speedup vs baseline: 1.1724x; 1.1724x over previous
//
#include <hip/hip_runtime.h>

#define DIM 4096
#define HD 128
#define NH 32
#define NKV 8
#define SEQ 2048
#define BATCH 2
#define MTOT (BATCH*SEQ)   // 4096 rows total
#define GK DIM             // K dim of every GEMM

typedef __bf16 bf16;
typedef __bf16 bf16x4 __attribute__((ext_vector_type(4)));
typedef __bf16 bf16x8 __attribute__((ext_vector_type(8)));
typedef float f32x4 __attribute__((ext_vector_type(4)));

__device__ __forceinline__ void gload_lds16(const void* g, void* l) {
    __builtin_amdgcn_global_load_lds(
        (const __attribute__((address_space(1))) void*)g,
        (__attribute__((address_space(3))) void*)l, 16, 0, 0);
}

// ---------------- fp32 -> bf16 flat convert (x) ----------------
__global__ __launch_bounds__(256) void conv_bf16(const float* __restrict__ in,
                                                 bf16* __restrict__ out, int n8) {
    int i = blockIdx.x * 256 + threadIdx.x;
    if (i >= n8) return;
    const float4* p = (const float4*)(in + (size_t)i * 8);
    float4 a = p[0], b = p[1];
    bf16x8 v;
    v[0]=(bf16)a.x; v[1]=(bf16)a.y; v[2]=(bf16)a.z; v[3]=(bf16)a.w;
    v[4]=(bf16)b.x; v[5]=(bf16)b.y; v[6]=(bf16)b.z; v[7]=(bf16)b.w;
    *(bf16x8*)(out + (size_t)i * 8) = v;
}

// ---------------- fp32 [K][N] -> bf16 [N][K] transpose-convert ----------------
__global__ __launch_bounds__(256) void tconv(const float* __restrict__ in,
                                             bf16* __restrict__ out, int N, int K) {
    __shared__ float t[32][33];
    int bx = blockIdx.x, by = blockIdx.y;
    int tx = threadIdx.x, ty = threadIdx.y;
    int col = bx * 32 + tx;
#pragma unroll
    for (int r = 0; r < 4; ++r) {
        int row = by * 32 + ty + r * 8;
        t[ty + r * 8][tx] = in[(size_t)row * N + col];
    }
    __syncthreads();
#pragma unroll
    for (int r = 0; r < 4; ++r) {
        int n = bx * 32 + ty + r * 8;
        int k = by * 32 + tx;
        out[(size_t)n * K + k] = (bf16)t[tx][ty + r * 8];
    }
}

// ---------------- RoPE in-place on bf16 buffer ----------------
__global__ __launch_bounds__(256) void rope_k(bf16* __restrict__ buf, int shift, int n8) {
    int i = blockIdx.x * 256 + threadIdx.x;
    if (i >= n8) return;
    size_t base = (size_t)i * 8;
    int col = (int)(base & ((1u << shift) - 1));
    int pos = (int)((base >> shift) & (SEQ - 1));
    int d0 = col & (HD - 1);
    bf16x8 v = *(const bf16x8*)(buf + base);
    float f[8];
#pragma unroll
    for (int j = 0; j < 8; ++j) f[j] = (float)v[j];
    const float nl2t = -13.287712379549449f / 64.f;  // -log2(theta)/(HD/2)
#pragma unroll
    for (int j = 0; j < 4; ++j) {
        float inv = exp2f(nl2t * (float)((d0 >> 1) + j));
        float ang = (float)pos * inv;
        float sn, cs;
        sincosf(ang, &sn, &cs);
        float x0 = f[2 * j], x1 = f[2 * j + 1];
        f[2 * j]     = x0 * cs - x1 * sn;
        f[2 * j + 1] = x0 * sn + x1 * cs;
    }
    bf16x8 ov;
#pragma unroll
    for (int j = 0; j < 8; ++j) ov[j] = (bf16)f[j];
    *(bf16x8*)(buf + base) = ov;
}

// ---------------- bf16 GEMM: C[M,N] = A[M,K] * Bt[N,K]^T  (m97 structure) ----
// used for the small-N projections (K, V) where the 256^2 grid would underfill.
template <bool F32OUT>
__global__ __launch_bounds__(256) void gemm_bt(const bf16* __restrict__ A,
                                               const bf16* __restrict__ Bt,
                                               void* __restrict__ out0, int N) {
    __shared__ alignas(16) bf16 sA[2][128 * 32];
    __shared__ alignas(16) bf16 sB[2][128 * 32];
    const int tid = threadIdx.x;
    const int lane = tid & 63, wid = tid >> 6;
    const int wm = wid >> 1, wn = wid & 1;
    const int m0 = blockIdx.y * 128, n0 = blockIdx.x * 128;

    auto stage = [&](int buf, int kt) {
#pragma unroll
        for (int it = 0; it < 2; ++it) {
            int slot = it * 256 + tid;
            int row = slot >> 2, s = slot & 3;
            gload_lds16(A + (size_t)(m0 + row) * GK + kt * 32 + s * 8, &sA[buf][slot * 8]);
            gload_lds16(Bt + (size_t)(n0 + row) * GK + kt * 32 + s * 8, &sB[buf][slot * 8]);
        }
    };

    f32x4 acc[4][4] = {};
    stage(0, 0);
    __syncthreads();
    int cur = 0;
    for (int kt = 0; kt < GK / 32; ++kt) {
        if (kt + 1 < GK / 32) stage(cur ^ 1, kt + 1);
        bf16x8 aF[4], bF[4];
#pragma unroll
        for (int i = 0; i < 4; ++i) {
            aF[i] = *(const bf16x8*)&sA[cur][(wm * 64 + i * 16 + (lane & 15)) * 32 + (lane >> 4) * 8];
            bF[i] = *(const bf16x8*)&sB[cur][(wn * 64 + i * 16 + (lane & 15)) * 32 + (lane >> 4) * 8];
        }
#pragma unroll
        for (int mi = 0; mi < 4; ++mi)
#pragma unroll
            for (int ni = 0; ni < 4; ++ni)
                acc[mi][ni] = __builtin_amdgcn_mfma_f32_16x16x32_bf16(aF[mi], bF[ni], acc[mi][ni], 0, 0, 0);
        __syncthreads();
        cur ^= 1;
    }
#pragma unroll
    for (int mi = 0; mi < 4; ++mi) {
#pragma unroll
        for (int ni = 0; ni < 4; ++ni) {
#pragma unroll
            for (int r = 0; r < 4; ++r) {
                int row = m0 + wm * 64 + mi * 16 + (lane >> 4) * 4 + r;
                int col = n0 + wn * 64 + ni * 16 + (lane & 15);
                float v = acc[mi][ni][r];
                if constexpr (F32OUT) {
                    ((float*)out0)[(size_t)row * N + col] = v;
                } else {
                    ((bf16*)out0)[(size_t)row * N + col] = (bf16)v;
                }
            }
        }
    }
}

// ---------------- 256x256 deep-pipelined GEMM (8-wave, 4 phases/K-tile) -----
// K-split half-tiles: region (buf, khalf) [256 x 32] bf16 = 16KB/operand.
// Phase p of K-tile t reads: ph0/ph1 -> K0(buf), ph2/ph3 -> K1(buf).
// Stage: ph0 issues K1(t+1), ph2 issues K0(t+2) -> first read 6 phases later.
// Counted s_waitcnt vmcnt(8) at end of odd phases only (never 0 in loop).
// LDS swizzle: 128B pair-rows, 16B slot ^= (pairrow & 7); inverse-swizzled
// global source keeps global_load_lds dest linear (both-sides involution).
template <bool F32OUT>
__global__ __launch_bounds__(512, 2) void gemm8(const bf16* __restrict__ A,
                                                const bf16* __restrict__ Bt,
                                                void* __restrict__ outp, int N) {
    __shared__ alignas(16) char sA[2][2][16384];
    __shared__ alignas(16) char sB[2][2][16384];
    const int tid = threadIdx.x, lane = tid & 63;
    const int wid = tid >> 6;
    const int wm = wid >> 2, wn = wid & 3;
    const int m0 = blockIdx.y * 256, n0 = blockIdx.x * 256;
    const int lrow = lane & 15, hc = lane >> 4;
    // swizzled per-lane byte offset within a region for frag reads
    const int rowbase = ((lrow >> 1) * 128) +
                        (((((lrow & 1) << 2) | hc) ^ (lrow >> 1)) << 4);
    const int NT = GK / 64;

    auto stageK = [&](int t, int kh) {
        if (t >= NT) return;
        const int b = t & 1;
#pragma unroll
        for (int it = 0; it < 2; ++it) {
            int sl = it * 512 + tid;              // 16B chunk id 0..1023
            int PRr = sl >> 3, ps = sl & 7;       // pair-row, phys slot
            int lsl = ps ^ (PRr & 7);             // logical slot (involution)
            int r = PRr * 2 + (lsl >> 2);         // logical row 0..255
            int cc = lsl & 3;                     // 16B col-chunk 0..3
            size_t koff = (size_t)t * 64 + kh * 32 + cc * 8;
            gload_lds16(A + (size_t)(m0 + r) * GK + koff, &sA[b][kh][sl * 16]);
            gload_lds16(Bt + (size_t)(n0 + r) * GK + koff, &sB[b][kh][sl * 16]);
        }
    };

    f32x4 acc[8][4] = {};

    // prologue: stage both halves of tiles 0 and 1 (16 loads/wave)
    stageK(0, 0); stageK(0, 1); stageK(1, 0); stageK(1, 1);
    asm volatile("s_waitcnt vmcnt(12)" ::: "memory");   // K0(0) ready
    __builtin_amdgcn_s_barrier();

    for (int t = 0; t < NT; ++t) {
        const int b = t & 1;
        const char* Ab = &sA[b][0][0];
        const char* Bb = &sB[b][0][0];
        bf16x8 af[8], bfr[2];

        // ---------- phase 0: ks=0, ni 0-1 ----------
#pragma unroll
        for (int mi = 0; mi < 8; ++mi)
            af[mi] = *(const bf16x8*)(Ab + wm * 8192 + mi * 1024 + rowbase);
        bfr[0] = *(const bf16x8*)(Bb + wn * 4096 + 0 * 1024 + rowbase);
        bfr[1] = *(const bf16x8*)(Bb + wn * 4096 + 1 * 1024 + rowbase);
        if (t > 0) stageK(t + 1, 1);
        __builtin_amdgcn_s_barrier();
        asm volatile("s_waitcnt lgkmcnt(0)" ::: "memory");
        __builtin_amdgcn_sched_barrier(0);
        __builtin_amdgcn_s_setprio(1);
#pragma unroll
        for (int mi = 0; mi < 8; ++mi) {
            acc[mi][0] = __builtin_amdgcn_mfma_f32_16x16x32_bf16(af[mi], bfr[0], acc[mi][0], 0, 0, 0);
            acc[mi][1] = __builtin_amdgcn_mfma_f32_16x16x32_bf16(af[mi], bfr[1], acc[mi][1], 0, 0, 0);
        }
        __builtin_amdgcn_s_setprio(0);
        __builtin_amdgcn_s_barrier();

        // ---------- phase 1: ks=0, ni 2-3 ----------
        bfr[0] = *(const bf16x8*)(Bb + wn * 4096 + 2 * 1024 + rowbase);
        bfr[1] = *(const bf16x8*)(Bb + wn * 4096 + 3 * 1024 + rowbase);
        __builtin_amdgcn_s_barrier();
        asm volatile("s_waitcnt lgkmcnt(0)" ::: "memory");
        __builtin_amdgcn_sched_barrier(0);
        __builtin_amdgcn_s_setprio(1);
#pragma unroll
        for (int mi = 0; mi < 8; ++mi) {
            acc[mi][2] = __builtin_amdgcn_mfma_f32_16x16x32_bf16(af[mi], bfr[0], acc[mi][2], 0, 0, 0);
            acc[mi][3] = __builtin_amdgcn_mfma_f32_16x16x32_bf16(af[mi], bfr[1], acc[mi][3], 0, 0, 0);
        }
        __builtin_amdgcn_s_setprio(0);
        asm volatile("s_waitcnt vmcnt(8)" ::: "memory");
        __builtin_amdgcn_s_barrier();

        // ---------- phase 2: ks=1, ni 0-1 ----------
#pragma unroll
        for (int mi = 0; mi < 8; ++mi)
            af[mi] = *(const bf16x8*)(Ab + 16384 + wm * 8192 + mi * 1024 + rowbase);
        bfr[0] = *(const bf16x8*)(Bb + 16384 + wn * 4096 + 0 * 1024 + rowbase);
        bfr[1] = *(const bf16x8*)(Bb + 16384 + wn * 4096 + 1 * 1024 + rowbase);
        stageK(t + 2, 0);
        __builtin_amdgcn_s_barrier();
        asm volatile("s_waitcnt lgkmcnt(0)" ::: "memory");
        __builtin_amdgcn_sched_barrier(0);
        __builtin_amdgcn_s_setprio(1);
#pragma unroll
        for (int mi = 0; mi < 8; ++mi) {
            acc[mi][0] = __builtin_amdgcn_mfma_f32_16x16x32_bf16(af[mi], bfr[0], acc[mi][0], 0, 0, 0);
            acc[mi][1] = __builtin_amdgcn_mfma_f32_16x16x32_bf16(af[mi], bfr[1], acc[mi][1], 0, 0, 0);
        }
        __builtin_amdgcn_s_setprio(0);
        __builtin_amdgcn_s_barrier();

        // ---------- phase 3: ks=1, ni 2-3 ----------
        bfr[0] = *(const bf16x8*)(Bb + 16384 + wn * 4096 + 2 * 1024 + rowbase);
        bfr[1] = *(const bf16x8*)(Bb + 16384 + wn * 4096 + 3 * 1024 + rowbase);
        __builtin_amdgcn_s_barrier();
        asm volatile("s_waitcnt lgkmcnt(0)" ::: "memory");
        __builtin_amdgcn_sched_barrier(0);
        __builtin_amdgcn_s_setprio(1);
#pragma unroll
        for (int mi = 0; mi < 8; ++mi) {
            acc[mi][2] = __builtin_amdgcn_mfma_f32_16x16x32_bf16(af[mi], bfr[0], acc[mi][2], 0, 0, 0);
            acc[mi][3] = __builtin_amdgcn_mfma_f32_16x16x32_bf16(af[mi], bfr[1], acc[mi][3], 0, 0, 0);
        }
        __builtin_amdgcn_s_setprio(0);
        asm volatile("s_waitcnt vmcnt(8)" ::: "memory");
        __builtin_amdgcn_s_barrier();
    }

    // epilogue
#pragma unroll
    for (int mi = 0; mi < 8; ++mi)
#pragma unroll
        for (int ni = 0; ni < 4; ++ni)
#pragma unroll
            for (int r = 0; r < 4; ++r) {
                int row = m0 + wm * 128 + mi * 16 + hc * 4 + r;
                int col = n0 + wn * 64 + ni * 16 + lrow;
                if constexpr (F32OUT)
                    ((float*)outp)[(size_t)row * N + col] = acc[mi][ni][r];
                else
                    ((bf16*)outp)[(size_t)row * N + col] = (bf16)acc[mi][ni][r];
            }
}

// ---------------- flash attention, GQA, causal ----------------
// grid: 512 = b(2) * h(32) * pair(8); 8 waves x 16 q-rows = 128 q-rows/pass;
// each block runs two passes (q-tile pr and 15-pr) -> exactly 34 KV rounds each.
// Swapped QK^T (S^T): softmax rows lane-local, P-writes packed b64.
__global__ __launch_bounds__(512, 4) void attn_fwd(const bf16* __restrict__ q,
                                                   const bf16* __restrict__ k,
                                                   const bf16* __restrict__ vt,
                                                   bf16* __restrict__ o) {
    __shared__ alignas(16) bf16 sK[2][64 * 128];   // [kv][d], XOR-swizzled source
    __shared__ alignas(16) bf16 sV[2][128 * 64];   // [d][kv], XOR-swizzled source
    __shared__ alignas(16) bf16 sP[8][16 * 64];    // per-wave P[q][kv], swizzled
    const int tid = threadIdx.x, lane = tid & 63, wid = tid >> 6;
    const int bi = blockIdx.x;
    const int pr = bi & 7;
    const int h = (bi >> 3) & 31;
    const int b = bi >> 8;
    const int kvh = h >> 2;
    const float scale = 0.08838834764831845f;  // 1/sqrt(128)

    const bf16* kb0 = k + (size_t)b * SEQ * (NKV * HD) + kvh * HD;
    const bf16* vb0 = vt + (size_t)(kvh * HD) * MTOT + (size_t)b * SEQ;

    auto stage = [&](int bf, int tt) {
        // K tile [64][128]: 1024 16B-slots, src slot = phys ^ (row&7)
#pragma unroll
        for (int it = 0; it < 2; ++it) {
            int slot = it * 512 + tid;
            int row = slot >> 4, s = slot & 15;
            gload_lds16(kb0 + (size_t)(tt * 64 + row) * (NKV * HD) + ((s ^ (row & 7)) * 8),
                        &sK[bf][slot * 8]);
        }
        // V^T tile [128][64] from vt[vdim][token] (row stride MTOT)
#pragma unroll
        for (int it = 0; it < 2; ++it) {
            int slot = it * 512 + tid;
            int row = slot >> 3, s = slot & 7;
            gload_lds16(vb0 + (size_t)row * MTOT + tt * 64 + ((s ^ (row & 7)) * 8),
                        &sV[bf][slot * 8]);
        }
    };

    auto pass = [&](int qt) {
        const int qb0 = qt * 128;
        const int nt = 2 * qt + 2;
        const bf16* qp = q + ((size_t)(b * SEQ + qb0 + wid * 16 + (lane & 15))) * DIM
                           + h * HD + (lane >> 4) * 8;
        bf16x8 aQ[4];
#pragma unroll
        for (int ks = 0; ks < 4; ++ks) aQ[ks] = *(const bf16x8*)(qp + ks * 32);

        f32x4 accO[8] = {};
        float m_r = -1e30f, l_r = 0.f;   // per-lane: q-col = lane&15 (uniform over hi)
        const int qglob = qb0 + wid * 16 + (lane & 15);
        char* pb = (char*)&sP[wid][0];
        const int q7s = (lane & 7) << 4;
        const int hi = lane >> 4;

        stage(0, 0);
        __syncthreads();
        int cur = 0;
        for (int tt = 0; tt < nt; ++tt) {
            if (tt + 1 < nt) stage(cur ^ 1, tt + 1);
            // skip tiles fully above this wave's diagonal (identity contribution)
            if (tt * 64 <= qb0 + wid * 16 + 15) {
                // S^T = mfma(K, Q): frag nt2 -> rows kv = tt*64+nt2*16+hi*4+r, col q = lane&15
                f32x4 accS[4] = {};
#pragma unroll
                for (int nt2 = 0; nt2 < 4; ++nt2) {
                    int kr = nt2 * 16 + (lane & 15);
#pragma unroll
                    for (int ks = 0; ks < 4; ++ks) {
                        int slog = ks * 4 + hi;
                        bf16x8 bK = *(const bf16x8*)&sK[cur][kr * 128 + ((slog ^ (kr & 7)) * 8)];
                        accS[nt2] = __builtin_amdgcn_mfma_f32_16x16x32_bf16(bK, aQ[ks], accS[nt2], 0, 0, 0);
                    }
                }

                // scale + causal mask + lane-local max over 16 kv values
                const bool diag = (tt * 64 + 63 > qb0 + wid * 16);
                const int kvb = tt * 64 + hi * 4;
                float mx = -1e30f;
#pragma unroll
                for (int nt2 = 0; nt2 < 4; ++nt2)
#pragma unroll
                    for (int r = 0; r < 4; ++r) {
                        float v = accS[nt2][r] * scale;
                        if (diag && (kvb + nt2 * 16 + r > qglob)) v = -1e30f;
                        accS[nt2][r] = v;
                        mx = fmaxf(mx, v);
                    }
                mx = fmaxf(mx, __shfl_xor(mx, 16, 64));
                mx = fmaxf(mx, __shfl_xor(mx, 32, 64));

                float mn = fmaxf(m_r, mx);
                float al = __expf(m_r - mn);
                m_r = mn;
                float rs = 0.f;
#pragma unroll
                for (int nt2 = 0; nt2 < 4; ++nt2)
#pragma unroll
                    for (int r = 0; r < 4; ++r) {
                        float p = __expf(accS[nt2][r] - mn);
                        accS[nt2][r] = p;
                        rs += p;
                    }
                rs += __shfl_xor(rs, 16, 64);
                rs += __shfl_xor(rs, 32, 64);
                l_r = l_r * al + rs;

                // rescale accO: its q-row for reg r is hi*4+r -> fetch al from lane hi*4+r
                float al4[4];
#pragma unroll
                for (int r = 0; r < 4; ++r) al4[r] = __shfl(al, hi * 4 + r, 64);
#pragma unroll
                for (int d2 = 0; d2 < 8; ++d2)
#pragma unroll
                    for (int r = 0; r < 4; ++r) accO[d2][r] *= al4[r];

                // P-write: lane holds 4 contiguous kv per frag -> b64 stores
                // byte = q*128 + ((kvl*2) ^ ((q&7)<<4)), q = lane&15
#pragma unroll
                for (int nt2 = 0; nt2 < 4; ++nt2) {
                    bf16x4 pv;
                    pv[0] = (bf16)accS[nt2][0]; pv[1] = (bf16)accS[nt2][1];
                    pv[2] = (bf16)accS[nt2][2]; pv[3] = (bf16)accS[nt2][3];
                    *(bf16x4*)(pb + (lane & 15) * 128 + ((nt2 * 32 + hi * 8) ^ q7s)) = pv;
                }

                // PV: O[16 x 128] += P[16 x 64] * V[64 x 128]
                bf16x8 aP[2];
#pragma unroll
                for (int kk = 0; kk < 2; ++kk)
                    aP[kk] = *(const bf16x8*)(pb + (lane & 15) * 128 + ((kk * 64 + hi * 16) ^ q7s));
#pragma unroll
                for (int d2 = 0; d2 < 8; ++d2) {
#pragma unroll
                    for (int kk = 0; kk < 2; ++kk) {
                        int dv = d2 * 16 + (lane & 15);
                        int phys = (kk * 4 + hi) ^ (dv & 7);
                        bf16x8 bV = *(const bf16x8*)&sV[cur][dv * 64 + phys * 8];
                        accO[d2] = __builtin_amdgcn_mfma_f32_16x16x32_bf16(aP[kk], bV, accO[d2], 0, 0, 0);
                    }
                }
            }
            __syncthreads();
            cur ^= 1;
        }

        // epilogue: normalize + store bf16 (accO q-row for reg r = hi*4+r)
        float linv[4];
#pragma unroll
        for (int r = 0; r < 4; ++r) linv[r] = 1.f / __shfl(l_r, hi * 4 + r, 64);
        size_t orow = (size_t)(b * SEQ + qb0 + wid * 16 + hi * 4) * DIM
                    + h * HD + (lane & 15);
#pragma unroll
        for (int d2 = 0; d2 < 8; ++d2)
#pragma unroll
            for (int r = 0; r < 4; ++r)
                o[orow + (size_t)r * DIM + d2 * 16] = (bf16)(accO[d2][r] * linv[r]);
    };

    pass(pr);
    pass(15 - pr);
}

// ---------------- launch ----------------
extern "C" void kernel_launch(void* const* d_in, const int* in_sizes, int n_in,
                              void* d_out, int out_size, void* d_ws, size_t ws_size,
                              hipStream_t stream) {
    const float* x  = (const float*)d_in[0];
    const float* wq = (const float*)d_in[1];
    const float* wk = (const float*)d_in[2];
    const float* wv = (const float*)d_in[3];
    const float* wo = (const float*)d_in[4];
    float* out = (float*)d_out;

    char* ws = (char*)d_ws;
    size_t off = 0;
    bf16* xb  = (bf16*)(ws + off); off += (size_t)MTOT * DIM * 2;   // 32 MiB (reused as attn_out)
    bf16* wqt = (bf16*)(ws + off); off += (size_t)DIM * DIM * 2;    // 32 MiB (reused as wo_t)
    bf16* wkt = (bf16*)(ws + off); off += (size_t)1024 * DIM * 2;   // 8 MiB
    bf16* wvt = (bf16*)(ws + off); off += (size_t)1024 * DIM * 2;   // 8 MiB
    bf16* qb  = (bf16*)(ws + off); off += (size_t)MTOT * DIM * 2;   // 32 MiB
    bf16* kb  = (bf16*)(ws + off); off += (size_t)MTOT * 1024 * 2;  // 8 MiB
    bf16* vtb = (bf16*)(ws + off); off += (size_t)MTOT * 1024 * 2;  // 8 MiB  V^T [1024][4096]
    bf16* ao = xb;  // attention output reuses x_bf16

    dim3 tb(32, 8);
    conv_bf16<<<(MTOT * DIM / 8) / 256, 256, 0, stream>>>(x, xb, MTOT * DIM / 8);
    tconv<<<dim3(DIM / 32, DIM / 32), tb, 0, stream>>>(wq, wqt, DIM, DIM);
    tconv<<<dim3(1024 / 32, DIM / 32), tb, 0, stream>>>(wk, wkt, 1024, DIM);
    tconv<<<dim3(1024 / 32, DIM / 32), tb, 0, stream>>>(wv, wvt, 1024, DIM);

    // Q proj: 4096x4096x4096 on the 256^2 deep-pipelined kernel (256 blocks)
    gemm8<false><<<dim3(DIM / 256, MTOT / 256), 512, 0, stream>>>(xb, wqt, qb, DIM);
    // K proj (N=1024) and V^T proj (M=1024) on the 128^2 kernel (full 256-block grids)
    gemm_bt<false><<<dim3(1024 / 128, MTOT / 128), 256, 0, stream>>>(xb, wkt, kb, 1024);
    gemm_bt<false><<<dim3(MTOT / 128, 1024 / 128), 256, 0, stream>>>(wvt, xb, vtb, MTOT);

    rope_k<<<(MTOT * DIM / 8) / 256, 256, 0, stream>>>(qb, 12, MTOT * DIM / 8);
    rope_k<<<(MTOT * 1024 / 8) / 256, 256, 0, stream>>>(kb, 10, MTOT * 1024 / 8);

    tconv<<<dim3(DIM / 32, DIM / 32), tb, 0, stream>>>(wo, wqt, DIM, DIM);  // wo_t -> wqt space

    attn_fwd<<<BATCH * NH * 8, 512, 0, stream>>>(qb, kb, vtb, ao);

    // out proj: fp32 output on the 256^2 kernel
    gemm8<true><<<dim3(DIM / 256, MTOT / 256), 512, 0, stream>>>(ao, wqt, out, DIM);
}